// Round 1
// baseline (515.069 us; speedup 1.0000x reference)
//
#include <hip/hip_runtime.h>
#include <hip/hip_bf16.h>

#define N_NODES 65536
#define IN_CH 512
#define HIDDEN 256
#define OUT_CH 8
#define NUM_GRAPHS 32
#define MAX_LEN 4096
#define BN_EPS 1e-5f

using short8  = __attribute__((ext_vector_type(8))) short;
using floatx4 = __attribute__((ext_vector_type(4))) float;
typedef unsigned int u32;
typedef unsigned short u16;

__device__ inline u16 f2b(float f) {
    u32 u = __float_as_uint(f);
    u += 0x7FFFu + ((u >> 16) & 1u);
    return (u16)(u >> 16);
}
__device__ inline float gelu_f(float x) {
    return 0.5f * x * (1.0f + erff(x * 0.70710678118654752f));
}
__device__ inline void load_lds16(const void* g, void* l) {
    __builtin_amdgcn_global_load_lds(
        (const __attribute__((address_space(1))) u32*)g,
        (__attribute__((address_space(3))) u32*)l, 16, 0, 0);
}

// ---------------- BN stats: per-channel sum and sumsq ----------------
__global__ __launch_bounds__(256) void bn_stats_k(const float* __restrict__ x,
                                                  float* __restrict__ sum,
                                                  float* __restrict__ sumsq) {
    __shared__ float sA[512];
    __shared__ float sQ[512];
    int tid = threadIdx.x;
    int half = tid >> 7;       // 0/1 row-group
    int c = tid & 127;         // float4 column index (512ch = 128 float4)
    const float4* x4 = (const float4*)x;
    float4 s = make_float4(0.f, 0.f, 0.f, 0.f);
    float4 q = make_float4(0.f, 0.f, 0.f, 0.f);
    int row0 = blockIdx.x * 256;
    for (int r = half; r < 256; r += 2) {
        float4 v = x4[(size_t)(row0 + r) * 128 + c];
        s.x += v.x; s.y += v.y; s.z += v.z; s.w += v.w;
        q.x += v.x * v.x; q.y += v.y * v.y; q.z += v.z * v.z; q.w += v.w * v.w;
    }
    if (half == 1) {
        sA[c * 4 + 0] = s.x; sA[c * 4 + 1] = s.y; sA[c * 4 + 2] = s.z; sA[c * 4 + 3] = s.w;
        sQ[c * 4 + 0] = q.x; sQ[c * 4 + 1] = q.y; sQ[c * 4 + 2] = q.z; sQ[c * 4 + 3] = q.w;
    }
    __syncthreads();
    if (half == 0) {
        s.x += sA[c * 4 + 0]; s.y += sA[c * 4 + 1]; s.z += sA[c * 4 + 2]; s.w += sA[c * 4 + 3];
        q.x += sQ[c * 4 + 0]; q.y += sQ[c * 4 + 1]; q.z += sQ[c * 4 + 2]; q.w += sQ[c * 4 + 3];
        atomicAdd(&sum[c * 4 + 0], s.x); atomicAdd(&sum[c * 4 + 1], s.y);
        atomicAdd(&sum[c * 4 + 2], s.z); atomicAdd(&sum[c * 4 + 3], s.w);
        atomicAdd(&sumsq[c * 4 + 0], q.x); atomicAdd(&sumsq[c * 4 + 1], q.y);
        atomicAdd(&sumsq[c * 4 + 2], q.z); atomicAdd(&sumsq[c * 4 + 3], q.w);
    }
}

__global__ void bn_finalize_k(const float* __restrict__ sum, const float* __restrict__ sumsq,
                              const float* __restrict__ gamma, const float* __restrict__ beta,
                              float* __restrict__ scale, float* __restrict__ shift) {
    int c = threadIdx.x;   // 512 threads
    float mu = sum[c] * (1.0f / N_NODES);
    float var = sumsq[c] * (1.0f / N_NODES) - mu * mu;
    float sc = gamma[c] * rsqrtf(var + BN_EPS);
    scale[c] = sc;
    shift[c] = beta[c] - mu * sc;
}

// graph start offsets via binary search on sorted batch ids
__global__ void offsets_k(const int* __restrict__ batch, int* __restrict__ offsets) {
    int g = threadIdx.x;
    if (g >= NUM_GRAPHS) return;
    int lo = 0, hi = N_NODES;
    while (lo < hi) {
        int mid = (lo + hi) >> 1;
        if (batch[mid] < g) lo = mid + 1; else hi = mid;
    }
    offsets[g] = lo;
}

// normalize + cast to bf16
__global__ __launch_bounds__(256) void normcast_k(const float* __restrict__ x,
                                                  const float* __restrict__ scale,
                                                  const float* __restrict__ shift,
                                                  u16* __restrict__ xb) {
    int idx = blockIdx.x * 256 + threadIdx.x;   // float4 index, 8M total
    const float4* x4 = (const float4*)x;
    float4 v = x4[idx];
    int c4 = idx & 127;
    float4 sc = ((const float4*)scale)[c4];
    float4 sh = ((const float4*)shift)[c4];
    v.x = v.x * sc.x + sh.x;
    v.y = v.y * sc.y + sh.y;
    v.z = v.z * sc.z + sh.z;
    v.w = v.w * sc.w + sh.w;
    uint2 o;
    o.x = (u32)f2b(v.x) | ((u32)f2b(v.y) << 16);
    o.y = (u32)f2b(v.z) | ((u32)f2b(v.w) << 16);
    ((uint2*)xb)[idx] = o;
}

// transpose + cast weights: W [K, M] f32 -> WT [M, K] bf16.  M = 1<<mbits
__global__ __launch_bounds__(256) void tcast_k(const float* __restrict__ W,
                                               u16* __restrict__ WT,
                                               int kdim, int mbits) {
    int idx = blockIdx.x * 256 + threadIdx.x;
    int k = idx >> mbits;
    int m = idx & ((1 << mbits) - 1);
    if (k < kdim) WT[(size_t)m * kdim + k] = f2b(W[idx]);
}

// ---------------- GEMM: C[N,M] = act(A[N,K] @ BT[M,K]^T + bias) ----------------
// 128x128 block tile, BK=64, 4 waves (2x2), each wave 4x4 of 16x16x32 MFMA.
template <int DO_GELU>
__global__ __launch_bounds__(256) void gemm_bt_k(const u16* __restrict__ A,
                                                 const u16* __restrict__ BT,
                                                 const float* __restrict__ bias,
                                                 u16* __restrict__ C,
                                                 int K, int M) {
    __shared__ __align__(16) u16 As[128 * 64];
    __shared__ __align__(16) u16 Bs[128 * 64];
    int tid = threadIdx.x;
    int lane = tid & 63;
    int row0 = blockIdx.y * 128;
    int col0 = blockIdx.x * 128;
    int wave = tid >> 6;
    int wr = (wave >> 1) * 64;
    int wc = (wave & 1) * 64;

    floatx4 acc[4][4] = {};

    const int nkt = K >> 6;
    for (int kt = 0; kt < nkt; ++kt) {
        int k0 = kt << 6;
#pragma unroll
        for (int s = 0; s < 4; ++s) {
            int li = s * 256 + tid;
            int r = li >> 3;
            int cc = (li & 7) << 3;
            load_lds16(&A[(size_t)(row0 + r) * K + k0 + cc], &As[li * 8]);
            load_lds16(&BT[(size_t)(col0 + r) * K + k0 + cc], &Bs[li * 8]);
        }
        __syncthreads();
#pragma unroll
        for (int ks = 0; ks < 2; ++ks) {
            int kk = ks * 32 + (lane >> 4) * 8;
            short8 af[4], bg[4];
#pragma unroll
            for (int i = 0; i < 4; ++i)
                af[i] = *(const short8*)&As[(wr + i * 16 + (lane & 15)) * 64 + kk];
#pragma unroll
            for (int j = 0; j < 4; ++j)
                bg[j] = *(const short8*)&Bs[(wc + j * 16 + (lane & 15)) * 64 + kk];
#pragma unroll
            for (int i = 0; i < 4; ++i)
#pragma unroll
                for (int j = 0; j < 4; ++j)
                    acc[i][j] = __builtin_amdgcn_mfma_f32_16x16x32_bf16(af[i], bg[j], acc[i][j], 0, 0, 0);
        }
        __syncthreads();
    }
    // epilogue: C/D layout col=lane&15, row=(lane>>4)*4+reg
    int ccol = lane & 15;
    int crow = (lane >> 4) * 4;
#pragma unroll
    for (int j = 0; j < 4; ++j) {
        int c = col0 + wc + j * 16 + ccol;
        float b = bias[c];
#pragma unroll
        for (int i = 0; i < 4; ++i) {
            int r = row0 + wr + i * 16 + crow;
#pragma unroll
            for (int reg = 0; reg < 4; ++reg) {
                float v = acc[i][j][reg] + b;
                if (DO_GELU) v = gelu_f(v);
                C[(size_t)(r + reg) * M + c] = f2b(v);
            }
        }
    }
}

// fill entire output with head(bo) (value at padded positions)
__global__ __launch_bounds__(256) void fill_k(float* __restrict__ out,
                                              const float* __restrict__ bo,
                                              const float* __restrict__ alpha_p,
                                              const float* __restrict__ dyt_w,
                                              const float* __restrict__ dyt_b) {
    int idx = blockIdx.x * 256 + threadIdx.x;   // float4 index, 262144 total
    float alpha = alpha_p[0];
    int c0 = (idx * 4) & 7;
    float4 v;
    float* pv = &v.x;
#pragma unroll
    for (int e = 0; e < 4; ++e) {
        int c = c0 + e;
        float a = gelu_f(bo[c]);
        a = dyt_w[c] * tanhf(alpha * a) + dyt_b[c];
        pv[e] = tanhf(a);
    }
    ((float4*)out)[idx] = v;
}

// head: y = tanh(dyt_w*tanh(alpha*gelu(h3 @ Wo + bo)) + dyt_b), scattered to [pos, graph, ch]
__global__ __launch_bounds__(256) void head_k(const u16* __restrict__ h3,
                                              const float* __restrict__ Wo,
                                              const float* __restrict__ bo,
                                              const int* __restrict__ batch,
                                              const int* __restrict__ offsets,
                                              const float* __restrict__ alpha_p,
                                              const float* __restrict__ dyt_w,
                                              const float* __restrict__ dyt_b,
                                              float* __restrict__ out) {
    __shared__ float sWo[HIDDEN * OUT_CH];   // 8KB
    __shared__ int soff[NUM_GRAPHS];
    int tid = threadIdx.x;
#pragma unroll
    for (int i = 0; i < 8; ++i) sWo[i * 256 + tid] = Wo[i * 256 + tid];
    if (tid < NUM_GRAPHS) soff[tid] = offsets[tid];
    __syncthreads();
    int n = blockIdx.x * 256 + tid;
    float acc[8];
#pragma unroll
    for (int c = 0; c < 8; ++c) acc[c] = bo[c];
    const uint4* hr = (const uint4*)(h3 + (size_t)n * HIDDEN);
#pragma unroll 4
    for (int kk = 0; kk < 32; ++kk) {
        uint4 v = hr[kk];
        u32 u[4] = {v.x, v.y, v.z, v.w};
#pragma unroll
        for (int p = 0; p < 4; ++p) {
            float h0 = __uint_as_float(u[p] << 16);
            float h1 = __uint_as_float(u[p] & 0xFFFF0000u);
            const float* w0 = &sWo[(kk * 8 + p * 2) * 8];
            const float* w1 = w0 + 8;
#pragma unroll
            for (int c = 0; c < 8; ++c) acc[c] += h0 * w0[c];
#pragma unroll
            for (int c = 0; c < 8; ++c) acc[c] += h1 * w1[c];
        }
    }
    float alpha = alpha_p[0];
    int g = batch[n];
    int p = n - soff[g];
    float res[8];
#pragma unroll
    for (int c = 0; c < 8; ++c) {
        float a = gelu_f(acc[c]);
        a = dyt_w[c] * tanhf(alpha * a) + dyt_b[c];
        res[c] = tanhf(a);
    }
    float4* o = (float4*)(out + ((size_t)p * NUM_GRAPHS + g) * OUT_CH);
    o[0] = make_float4(res[0], res[1], res[2], res[3]);
    o[1] = make_float4(res[4], res[5], res[6], res[7]);
}

extern "C" void kernel_launch(void* const* d_in, const int* in_sizes, int n_in,
                              void* d_out, int out_size, void* d_ws, size_t ws_size,
                              hipStream_t stream) {
    (void)in_sizes; (void)n_in; (void)out_size; (void)ws_size;
    const float* x_res = (const float*)d_in[0];
    const int*   batch = (const int*)d_in[1];
    const float* gamma = (const float*)d_in[2];
    const float* beta  = (const float*)d_in[3];
    const float* W1    = (const float*)d_in[4];
    const float* b1    = (const float*)d_in[5];
    const float* W2    = (const float*)d_in[6];
    const float* b2    = (const float*)d_in[7];
    const float* W3    = (const float*)d_in[8];
    const float* b3    = (const float*)d_in[9];
    const float* Wo    = (const float*)d_in[10];
    const float* bo    = (const float*)d_in[11];
    const float* alpha = (const float*)d_in[12];
    const float* dyt_w = (const float*)d_in[13];
    const float* dyt_b = (const float*)d_in[14];
    float* out = (float*)d_out;

    char* ws = (char*)d_ws;
    float* sumv  = (float*)(ws + 0);
    float* sumsq = (float*)(ws + 2048);
    float* scale = (float*)(ws + 4096);
    float* shift = (float*)(ws + 6144);
    int*   offs  = (int*)(ws + 8192);
    u16* W1T = (u16*)(ws + 16384);                       // 512KB
    u16* W2T = (u16*)(ws + 16384 + 524288);              // 256KB
    u16* W3T = (u16*)(ws + 16384 + 524288 + 262144);     // 128KB
    const size_t MB = 1024 * 1024;
    u16* xb = (u16*)(ws + 2 * MB);      // 64MB  [2,66)
    u16* h1 = (u16*)(ws + 66 * MB);     // 64MB  [66,130)
    u16* h2 = (u16*)(ws + 2 * MB);      // 32MB  (aliases xb; xb dead after GEMM1)
    u16* h3 = (u16*)(ws + 66 * MB);     // 32MB  (aliases h1; h1 dead after GEMM2)

    hipMemsetAsync(d_ws, 0, 16384, stream);
    bn_stats_k<<<256, 256, 0, stream>>>(x_res, sumv, sumsq);
    bn_finalize_k<<<1, 512, 0, stream>>>(sumv, sumsq, gamma, beta, scale, shift);
    offsets_k<<<1, 32, 0, stream>>>(batch, offs);
    normcast_k<<<32768, 256, 0, stream>>>(x_res, scale, shift, xb);
    tcast_k<<<(512 * 512) / 256, 256, 0, stream>>>(W1, W1T, 512, 9);
    tcast_k<<<(512 * 256) / 256, 256, 0, stream>>>(W2, W2T, 512, 8);
    tcast_k<<<(256 * 256) / 256, 256, 0, stream>>>(W3, W3T, 256, 8);
    gemm_bt_k<1><<<dim3(4, 512), 256, 0, stream>>>(xb, W1T, b1, h1, 512, 512);
    gemm_bt_k<1><<<dim3(2, 512), 256, 0, stream>>>(h1, W2T, b2, h2, 512, 256);
    gemm_bt_k<0><<<dim3(2, 512), 256, 0, stream>>>(h2, W3T, b3, h3, 256, 256);
    fill_k<<<1024, 256, 0, stream>>>(out, bo, alpha, dyt_w, dyt_b);
    head_k<<<256, 256, 0, stream>>>(h3, Wo, bo, batch, offs, alpha, dyt_w, dyt_b, out);
}

// Round 2
// 454.328 us; speedup vs baseline: 1.1337x; 1.1337x over previous
//
#include <hip/hip_runtime.h>
#include <hip/hip_bf16.h>

#define N_NODES 65536
#define IN_CH 512
#define HIDDEN 256
#define OUT_CH 8
#define NUM_GRAPHS 32
#define MAX_LEN 4096
#define BN_EPS 1e-5f
#define BN_BLOCKS 2048

using short8  = __attribute__((ext_vector_type(8))) short;
using floatx4 = __attribute__((ext_vector_type(4))) float;
typedef unsigned int u32;
typedef unsigned short u16;

__device__ inline u16 f2b(float f) {
    u32 u = __float_as_uint(f);
    u += 0x7FFFu + ((u >> 16) & 1u);
    return (u16)(u >> 16);
}
__device__ inline float gelu_f(float x) {
    return 0.5f * x * (1.0f + erff(x * 0.70710678118654752f));
}
__device__ inline void load_lds16(const void* g, void* l) {
    __builtin_amdgcn_global_load_lds(
        (const __attribute__((address_space(1))) u32*)g,
        (__attribute__((address_space(3))) u32*)l, 16, 0, 0);
}

// ---- fused: per-channel sum/sumsq partials + raw bf16 cast of x ----
// 2048 blocks x 32 rows. partials row b: float4 idx g holds
// (sum[2g], sq[2g], sum[2g+1], sq[2g+1]) for channels 2g,2g+1 (g=0..255).
__global__ __launch_bounds__(256) void statscast_k(const float* __restrict__ x,
                                                   u16* __restrict__ xb,
                                                   float4* __restrict__ partials) {
    __shared__ float4 sS[128];
    __shared__ float4 sQ[128];
    int tid = threadIdx.x;
    int half = tid >> 7;
    int c = tid & 127;                  // float4 column (512ch = 128 float4)
    const float4* x4 = (const float4*)x;
    uint2* xb2 = (uint2*)xb;
    float4 s = make_float4(0.f, 0.f, 0.f, 0.f);
    float4 q = make_float4(0.f, 0.f, 0.f, 0.f);
    int row0 = blockIdx.x * 32;
#pragma unroll
    for (int r = half; r < 32; r += 2) {
        size_t off = (size_t)(row0 + r) * 128 + c;
        float4 v = x4[off];
        s.x += v.x; s.y += v.y; s.z += v.z; s.w += v.w;
        q.x += v.x * v.x; q.y += v.y * v.y; q.z += v.z * v.z; q.w += v.w * v.w;
        uint2 o;
        o.x = (u32)f2b(v.x) | ((u32)f2b(v.y) << 16);
        o.y = (u32)f2b(v.z) | ((u32)f2b(v.w) << 16);
        xb2[off] = o;
    }
    if (half == 1) { sS[c] = s; sQ[c] = q; }
    __syncthreads();
    if (half == 0) {
        float4 s2 = sS[c], q2 = sQ[c];
        s.x += s2.x; s.y += s2.y; s.z += s2.z; s.w += s2.w;
        q.x += q2.x; q.y += q2.y; q.z += q2.z; q.w += q2.w;
        float4 o0 = make_float4(s.x, q.x, s.y, q.y);
        float4 o1 = make_float4(s.z, q.z, s.w, q.w);
        partials[(size_t)blockIdx.x * 256 + c * 2] = o0;
        partials[(size_t)blockIdx.x * 256 + c * 2 + 1] = o1;
    }
}

// ---- reduce partials -> scale/shift (block g handles channels 2g, 2g+1) ----
__global__ __launch_bounds__(256) void bn_reduce_k(const float4* __restrict__ partials,
                                                   const float* __restrict__ gamma,
                                                   const float* __restrict__ beta,
                                                   float* __restrict__ scale,
                                                   float* __restrict__ shift) {
    __shared__ float4 sd[256];
    int tid = threadIdx.x;
    int g = blockIdx.x;
    float4 a = make_float4(0.f, 0.f, 0.f, 0.f);
    for (int r = tid; r < BN_BLOCKS; r += 256) {
        float4 v = partials[(size_t)r * 256 + g];
        a.x += v.x; a.y += v.y; a.z += v.z; a.w += v.w;
    }
    sd[tid] = a;
    __syncthreads();
    for (int st = 128; st > 0; st >>= 1) {
        if (tid < st) {
            float4 b = sd[tid + st];
            float4 m = sd[tid];
            m.x += b.x; m.y += b.y; m.z += b.z; m.w += b.w;
            sd[tid] = m;
        }
        __syncthreads();
    }
    if (tid == 0) {
        float4 t = sd[0];
        int c0 = g * 2, c1 = g * 2 + 1;
        const float inv = 1.0f / N_NODES;
        float mu0 = t.x * inv, var0 = t.y * inv - mu0 * mu0;
        float mu1 = t.z * inv, var1 = t.w * inv - mu1 * mu1;
        float sc0 = gamma[c0] * rsqrtf(var0 + BN_EPS);
        float sc1 = gamma[c1] * rsqrtf(var1 + BN_EPS);
        scale[c0] = sc0; shift[c0] = beta[c0] - mu0 * sc0;
        scale[c1] = sc1; shift[c1] = beta[c1] - mu1 * sc1;
    }
}

// ---- weight prep: W1T = bf16(scale[k]*W1[k,m]) [M,K]; W2T/W3T plain; offsets ----
__global__ __launch_bounds__(256) void wprep_k(const float* __restrict__ W1,
                                               const float* __restrict__ W2,
                                               const float* __restrict__ W3,
                                               const float* __restrict__ scale,
                                               u16* __restrict__ W1T,
                                               u16* __restrict__ W2T,
                                               u16* __restrict__ W3T,
                                               const int* __restrict__ batch,
                                               int* __restrict__ offsets) {
    int idx = blockIdx.x * 256 + threadIdx.x;
    if (idx < 262144) {                       // W1 [512,512]
        int k = idx >> 9, m = idx & 511;
        W1T[(size_t)m * 512 + k] = f2b(scale[k] * W1[idx]);
    } else if (idx < 262144 + 131072) {       // W2 [512,256]
        int i = idx - 262144;
        int k = i >> 8, m = i & 255;
        W2T[(size_t)m * 512 + k] = f2b(W2[i]);
    } else {                                  // W3 [256,256]
        int i = idx - 393216;
        int k = i >> 8, m = i & 255;
        W3T[(size_t)m * 256 + k] = f2b(W3[i]);
    }
    if (blockIdx.x == 0 && threadIdx.x < NUM_GRAPHS) {
        int gph = threadIdx.x;
        int lo = 0, hi = N_NODES;
        while (lo < hi) {
            int mid = (lo + hi) >> 1;
            if (batch[mid] < gph) lo = mid + 1; else hi = mid;
        }
        offsets[gph] = lo;
    }
}

// ---- folded bias: b1f[m] = b1[m] + sum_k shift[k]*W1[k,m] ----
__global__ __launch_bounds__(128) void b1fold_k(const float* __restrict__ W1,
                                                const float* __restrict__ b1,
                                                const float* __restrict__ shift,
                                                float* __restrict__ b1f) {
    int m = blockIdx.x * 128 + threadIdx.x;   // 4 blocks x 128 = 512
    float acc = b1[m];
#pragma unroll 16
    for (int k = 0; k < 512; ++k) acc += shift[k] * W1[k * 512 + m];
    b1f[m] = acc;
}

// ---------------- GEMM: C[N,M] = act(A[N,K] @ BT[M,K]^T + bias) ----------------
// 128x128 block tile, BK=64, 4 waves (2x2), each wave 4x4 of 16x16x32 MFMA.
template <int DO_GELU>
__global__ __launch_bounds__(256) void gemm_bt_k(const u16* __restrict__ A,
                                                 const u16* __restrict__ BT,
                                                 const float* __restrict__ bias,
                                                 u16* __restrict__ C,
                                                 int K, int M) {
    __shared__ __align__(16) u16 As[128 * 64];
    __shared__ __align__(16) u16 Bs[128 * 64];
    int tid = threadIdx.x;
    int lane = tid & 63;
    int row0 = blockIdx.y * 128;
    int col0 = blockIdx.x * 128;
    int wave = tid >> 6;
    int wr = (wave >> 1) * 64;
    int wc = (wave & 1) * 64;

    floatx4 acc[4][4] = {};

    const int nkt = K >> 6;
    for (int kt = 0; kt < nkt; ++kt) {
        int k0 = kt << 6;
#pragma unroll
        for (int s = 0; s < 4; ++s) {
            int li = s * 256 + tid;
            int r = li >> 3;
            int cc = (li & 7) << 3;
            load_lds16(&A[(size_t)(row0 + r) * K + k0 + cc], &As[li * 8]);
            load_lds16(&BT[(size_t)(col0 + r) * K + k0 + cc], &Bs[li * 8]);
        }
        __syncthreads();
#pragma unroll
        for (int ks = 0; ks < 2; ++ks) {
            int kk = ks * 32 + (lane >> 4) * 8;
            short8 af[4], bg[4];
#pragma unroll
            for (int i = 0; i < 4; ++i)
                af[i] = *(const short8*)&As[(wr + i * 16 + (lane & 15)) * 64 + kk];
#pragma unroll
            for (int j = 0; j < 4; ++j)
                bg[j] = *(const short8*)&Bs[(wc + j * 16 + (lane & 15)) * 64 + kk];
#pragma unroll
            for (int i = 0; i < 4; ++i)
#pragma unroll
                for (int j = 0; j < 4; ++j)
                    acc[i][j] = __builtin_amdgcn_mfma_f32_16x16x32_bf16(af[i], bg[j], acc[i][j], 0, 0, 0);
        }
        __syncthreads();
    }
    // epilogue: C/D layout col=lane&15, row=(lane>>4)*4+reg
    int ccol = lane & 15;
    int crow = (lane >> 4) * 4;
#pragma unroll
    for (int j = 0; j < 4; ++j) {
        int c = col0 + wc + j * 16 + ccol;
        float b = bias[c];
#pragma unroll
        for (int i = 0; i < 4; ++i) {
            int r = row0 + wr + i * 16 + crow;
#pragma unroll
            for (int reg = 0; reg < 4; ++reg) {
                float v = acc[i][j][reg] + b;
                if (DO_GELU) v = gelu_f(v);
                C[(size_t)(r + reg) * M + c] = f2b(v);
            }
        }
    }
}

// fill entire output with head(bo) (value at padded positions)
__global__ __launch_bounds__(256) void fill_k(float* __restrict__ out,
                                              const float* __restrict__ bo,
                                              const float* __restrict__ alpha_p,
                                              const float* __restrict__ dyt_w,
                                              const float* __restrict__ dyt_b) {
    int idx = blockIdx.x * 256 + threadIdx.x;   // float4 index, 262144 total
    float alpha = alpha_p[0];
    int c0 = (idx * 4) & 7;
    float4 v;
    float* pv = &v.x;
#pragma unroll
    for (int e = 0; e < 4; ++e) {
        int c = c0 + e;
        float a = gelu_f(bo[c]);
        a = dyt_w[c] * tanhf(alpha * a) + dyt_b[c];
        pv[e] = tanhf(a);
    }
    ((float4*)out)[idx] = v;
}

// head: y = tanh(dyt_w*tanh(alpha*gelu(h3 @ Wo + bo)) + dyt_b), scattered to [pos, graph, ch]
__global__ __launch_bounds__(256) void head_k(const u16* __restrict__ h3,
                                              const float* __restrict__ Wo,
                                              const float* __restrict__ bo,
                                              const int* __restrict__ batch,
                                              const int* __restrict__ offsets,
                                              const float* __restrict__ alpha_p,
                                              const float* __restrict__ dyt_w,
                                              const float* __restrict__ dyt_b,
                                              float* __restrict__ out) {
    __shared__ float sWo[HIDDEN * OUT_CH];   // 8KB
    __shared__ int soff[NUM_GRAPHS];
    int tid = threadIdx.x;
#pragma unroll
    for (int i = 0; i < 8; ++i) sWo[i * 256 + tid] = Wo[i * 256 + tid];
    if (tid < NUM_GRAPHS) soff[tid] = offsets[tid];
    __syncthreads();
    int n = blockIdx.x * 256 + tid;
    float acc[8];
#pragma unroll
    for (int c = 0; c < 8; ++c) acc[c] = bo[c];
    const uint4* hr = (const uint4*)(h3 + (size_t)n * HIDDEN);
#pragma unroll 4
    for (int kk = 0; kk < 32; ++kk) {
        uint4 v = hr[kk];
        u32 u[4] = {v.x, v.y, v.z, v.w};
#pragma unroll
        for (int p = 0; p < 4; ++p) {
            float h0 = __uint_as_float(u[p] << 16);
            float h1 = __uint_as_float(u[p] & 0xFFFF0000u);
            const float* w0 = &sWo[(kk * 8 + p * 2) * 8];
            const float* w1 = w0 + 8;
#pragma unroll
            for (int c = 0; c < 8; ++c) acc[c] += h0 * w0[c];
#pragma unroll
            for (int c = 0; c < 8; ++c) acc[c] += h1 * w1[c];
        }
    }
    float alpha = alpha_p[0];
    int g = batch[n];
    int p = n - soff[g];
    float res[8];
#pragma unroll
    for (int c = 0; c < 8; ++c) {
        float a = gelu_f(acc[c]);
        a = dyt_w[c] * tanhf(alpha * a) + dyt_b[c];
        res[c] = tanhf(a);
    }
    float4* o = (float4*)(out + ((size_t)p * NUM_GRAPHS + g) * OUT_CH);
    o[0] = make_float4(res[0], res[1], res[2], res[3]);
    o[1] = make_float4(res[4], res[5], res[6], res[7]);
}

extern "C" void kernel_launch(void* const* d_in, const int* in_sizes, int n_in,
                              void* d_out, int out_size, void* d_ws, size_t ws_size,
                              hipStream_t stream) {
    (void)in_sizes; (void)n_in; (void)out_size; (void)ws_size;
    const float* x_res = (const float*)d_in[0];
    const int*   batch = (const int*)d_in[1];
    const float* gamma = (const float*)d_in[2];
    const float* beta  = (const float*)d_in[3];
    const float* W1    = (const float*)d_in[4];
    const float* b1    = (const float*)d_in[5];
    const float* W2    = (const float*)d_in[6];
    const float* b2    = (const float*)d_in[7];
    const float* W3    = (const float*)d_in[8];
    const float* b3    = (const float*)d_in[9];
    const float* Wo    = (const float*)d_in[10];
    const float* bo    = (const float*)d_in[11];
    const float* alpha = (const float*)d_in[12];
    const float* dyt_w = (const float*)d_in[13];
    const float* dyt_b = (const float*)d_in[14];
    float* out = (float*)d_out;

    char* ws = (char*)d_ws;
    float* scale = (float*)(ws + 0);
    float* shift = (float*)(ws + 2048);
    float* b1f   = (float*)(ws + 4096);
    int*   offs  = (int*)(ws + 8192);
    u16* W1T = (u16*)(ws + 16384);                       // 512KB
    u16* W2T = (u16*)(ws + 16384 + 524288);              // 256KB
    u16* W3T = (u16*)(ws + 16384 + 524288 + 262144);     // 128KB
    const size_t MB = 1024 * 1024;
    u16* xb = (u16*)(ws + 2 * MB);              // 64MB  [2,66)
    u16* h1 = (u16*)(ws + 66 * MB);             // 64MB  [66,130)
    u16* h2 = (u16*)(ws + 2 * MB);              // 32MB  (aliases xb; dead after GEMM1)
    u16* h3 = (u16*)(ws + 66 * MB);             // 32MB  (aliases h1; dead after GEMM2)
    float4* partials = (float4*)(ws + 66 * MB); // 8MB   (aliases h1; dead before GEMM1)

    statscast_k<<<BN_BLOCKS, 256, 0, stream>>>(x_res, xb, partials);
    bn_reduce_k<<<256, 256, 0, stream>>>(partials, gamma, beta, scale, shift);
    wprep_k<<<1792, 256, 0, stream>>>(W1, W2, W3, scale, W1T, W2T, W3T, batch, offs);
    b1fold_k<<<4, 128, 0, stream>>>(W1, b1, shift, b1f);
    gemm_bt_k<1><<<dim3(4, 512), 256, 0, stream>>>(xb, W1T, b1f, h1, 512, 512);
    gemm_bt_k<1><<<dim3(2, 512), 256, 0, stream>>>(h1, W2T, b2, h2, 512, 256);
    gemm_bt_k<0><<<dim3(2, 512), 256, 0, stream>>>(h2, W3T, b3, h3, 256, 256);
    fill_k<<<1024, 256, 0, stream>>>(out, bo, alpha, dyt_w, dyt_b);
    head_k<<<256, 256, 0, stream>>>(h3, Wo, bo, batch, offs, alpha, dyt_w, dyt_b, out);
}